// Round 13
// baseline (438.716 us; speedup 1.0000x reference)
//
#include <hip/hip_runtime.h>
#include <hip/hip_cooperative_groups.h>

namespace cg = cooperative_groups;

#define N_PTS 1000000
#define H_DIM 200
#define W_DIM 70400
#define FILL_V -9999999.0f

typedef float v2f __attribute__((ext_vector_type(2)));

__device__ __forceinline__ v2f fma2(v2f a, v2f b, v2f c) {
    return __builtin_elementwise_fma(a, b, c);   // -> v_pk_fma_f32 on gfx950
}

// ---------------------------------------------------------------------------
// ONE cooperative kernel, three phases separated by grid.sync():
//   phase 0: zero counts[]            (replaces the hipMemsetAsync dispatch)
//   phase 1: per-point MLP + scatter  (R10's proven body: scalar s_load
//            weights, v2f packed math, layer4 fused; 96us, VGPR 60, no spill)
//   phase 2: per-column dedup+max     (R6's proven LDS 64-bit winner table)
// Rationale: R10's 3-dispatch total was 173.6us with only ~110us of kernel
// time -- ~55us was memset + inter-dispatch/graph overhead. Fusing removes
// two dispatch boundaries.
// Hard-won constraints baked in:
//  * weights MUST stream via wave-uniform s_load (vector-load variant: 11%
//    VALUBusy, 350us; LDS variant: AGPR shuffle; both falsified).
//  * per-thread live set MUST stay ~60 floats (2-pt variants spilled to
//    AGPR/scratch regardless of __launch_bounds__; worst 9 GB HBM traffic).
//  * winner-table init must cover all 200 rows (R4/R5 bug: 64 lanes need
//    4 strided passes).
// List entry: .x = value bits, .y = (point_index << 8) | row  (row<200<256).
// Last-write-wins scatter: point survives iff no LATER point hit (row,col).
// ---------------------------------------------------------------------------
__global__ void __launch_bounds__(256) fused_kernel(
    const float* __restrict__ input,        // [4][N]
    const int* __restrict__ tindex,         // [N][2] int32 (row, col)
    const float* __restrict__ w1, const float* __restrict__ b1,
    const float* __restrict__ w2, const float* __restrict__ b2,
    const float* __restrict__ w3, const float* __restrict__ b3,
    const float* __restrict__ w4, const float* __restrict__ b4,
    int* __restrict__ counts,               // [W]
    uint2* __restrict__ list,               // [W][maxk]
    int maxk,
    float* __restrict__ out)                // [W+1]
{
    cg::grid_group grid = cg::this_grid();
    const int tid      = blockIdx.x * 256 + threadIdx.x;
    const int nthreads = gridDim.x * 256;
    const bool empty   = (tindex[0] == -1);

    // ---------------- phase 0: zero the per-column counters ----------------
    for (int k = tid; k < W_DIM; k += nthreads) counts[k] = 0;
    grid.sync();

    // ---------------- phase 1: MLP + scatter (R10 body) ---------------------
    if (!empty) {
        const v2f* __restrict__ w1v = (const v2f*)w1;   // rows of 4 = 2 v2f
        const v2f* __restrict__ w2v = (const v2f*)w2;   // rows of 18 = 9 v2f
        const v2f* __restrict__ w3v = (const v2f*)w3;   // rows of 36 = 18 v2f

        for (int i = tid; i < N_PTS; i += nthreads) {
            const v2f x01 = { input[0 * N_PTS + i], input[1 * N_PTS + i] };
            const v2f x23 = { input[2 * N_PTS + i], input[3 * N_PTS + i] };

            v2f h1v[9];
#pragma unroll
            for (int o = 0; o < 18; ++o) {
                v2f acc = { b1[o], 0.0f };
                acc = fma2(w1v[o * 2 + 0], x01, acc);
                acc = fma2(w1v[o * 2 + 1], x23, acc);
                const float h = fmaxf(acc.x + acc.y, 0.0f);
                if (o & 1) h1v[o >> 1].y = h; else h1v[o >> 1].x = h;
            }

            v2f h2v[18];
#pragma unroll
            for (int o = 0; o < 36; ++o) {
                v2f acc = { b2[o], 0.0f };
#pragma unroll
                for (int q = 0; q < 9; ++q)
                    acc = fma2(w2v[o * 9 + q], h1v[q], acc);
                const float h = fmaxf(acc.x + acc.y, 0.0f);
                if (o & 1) h2v[o >> 1].y = h; else h2v[o >> 1].x = h;
            }

            float v = b4[0];
#pragma unroll
            for (int o = 0; o < 36; ++o) {
                v2f acc = { b3[o], 0.0f };
#pragma unroll
                for (int q = 0; q < 18; ++q)
                    acc = fma2(w3v[o * 18 + q], h2v[q], acc);
                v = fmaf(w4[o], fmaxf(acc.x + acc.y, 0.0f), v);
            }

            const int2 hw = ((const int2*)tindex)[i];   // (row, col)
            const int pos = atomicAdd(&counts[hw.y], 1);
            if (pos < maxk) {
                uint2 e;
                e.x = __float_as_uint(v);
                e.y = ((unsigned)i << 8) | (unsigned)hw.x;
                list[(size_t)hw.y * maxk + pos] = e;
            }
        }
    }
    __threadfence();          // make list/counts stores device-visible (XCDs)
    grid.sync();

    // ---------------- phase 2: per-column dedup + max (R6 body) -------------
    __shared__ unsigned long long rowwin[4][200];
    const int lane = threadIdx.x & 63;
    const int wv   = threadIdx.x >> 6;           // wave in block: 0..3
    unsigned long long* tbl = rowwin[wv];
    const int gw0    = blockIdx.x * 4 + wv;      // first column for this wave
    const int nwaves = gridDim.x * 4;
    const int iters  = (W_DIM + nwaves - 1) / nwaves;   // uniform trip count

    if (tid == 0) out[W_DIM] = empty ? 0.0f : 1.0f;     // flag output

    for (int it = 0; it < iters; ++it) {
        const int w = gw0 + it * nwaves;
        const bool active = (w < W_DIM) && !empty;

        tbl[lane]       = 0ull;                  // rows   0.. 63
        tbl[lane + 64]  = 0ull;                  // rows  64..127
        tbl[lane + 128] = 0ull;                  // rows 128..191
        if (lane < 8) tbl[lane + 192] = 0ull;    // rows 192..199
        __syncthreads();

        uint2 e = make_uint2(0u, 0u);
        bool have = false;
        if (active) {
            int c = counts[w];
            if (c > maxk) c = maxk;
            have = (lane < c);
            if (have) {
                e = list[(size_t)w * maxk + lane];
                const unsigned long long key64 =
                    ((unsigned long long)e.y << 32) | (unsigned long long)e.x;
                atomicMax(&tbl[e.y & 0xFFu], key64);
            }
        }
        __syncthreads();

        float v = FILL_V;
        if (have) {
            const unsigned long long winner = tbl[e.y & 0xFFu];
            v = __uint_as_float((unsigned)(winner & 0xFFFFFFFFull));
        }
#pragma unroll
        for (int off = 32; off > 0; off >>= 1)
            v = fmaxf(v, __shfl_down(v, off, 64));

        if (lane == 0 && w < W_DIM) out[w] = v;  // empty => FILL_V
    }
}

extern "C" void kernel_launch(void* const* d_in, const int* in_sizes, int n_in,
                              void* d_out, int out_size, void* d_ws, size_t ws_size,
                              hipStream_t stream) {
    const float* input  = (const float*)d_in[0];
    const int*   tindex = (const int*)d_in[1];   // int32 on device
    const float* w1 = (const float*)d_in[2];
    const float* b1 = (const float*)d_in[3];
    const float* w2 = (const float*)d_in[4];
    const float* b2 = (const float*)d_in[5];
    const float* w3 = (const float*)d_in[6];
    const float* b3 = (const float*)d_in[7];
    const float* w4 = (const float*)d_in[8];
    const float* b4 = (const float*)d_in[9];
    float* out = (float*)d_out;

    // workspace: counts [70400 int] | list [70400][maxk] uint2
    int*   counts = (int*)d_ws;
    uint2* list   = (uint2*)((char*)d_ws + (size_t)W_DIM * sizeof(int));

    size_t avail = (ws_size > (size_t)W_DIM * sizeof(int))
                       ? ws_size - (size_t)W_DIM * sizeof(int) : 0;
    int maxk = (int)(avail / ((size_t)W_DIM * sizeof(uint2)));
    if (maxk > 64) maxk = 64;
    if (maxk < 1)  maxk = 1;

    // cooperative grid: all blocks co-resident (validated by the runtime)
    int maxb = 0;
    hipOccupancyMaxActiveBlocksPerMultiprocessor(&maxb, fused_kernel, 256, 0);
    if (maxb < 1) maxb = 2;                  // conservative fallback
    int G = maxb * 256;                      // 256 CUs on MI355X
    if (G > 2048) G = 2048;

    void* args[] = {
        (void*)&input, (void*)&tindex,
        (void*)&w1, (void*)&b1, (void*)&w2, (void*)&b2,
        (void*)&w3, (void*)&b3, (void*)&w4, (void*)&b4,
        (void*)&counts, (void*)&list, (void*)&maxk, (void*)&out
    };
    hipLaunchCooperativeKernel(fused_kernel, dim3(G), dim3(256), args, 0, stream);
}